// Round 1
// baseline (532.399 us; speedup 1.0000x reference)
//
#include <hip/hip_runtime.h>
#include <hip/hip_bf16.h>

// LSTM cell, fused: gates = [x|h] @ [Wx;Wh] + b ; elementwise -> (h_new, c_new)
// N = 262144 rows, F=64, H=128, K=192, 512 gate columns.
// Strategy: bf16 MFMA (32x32x16), weights pre-swizzled to b-frag layout in d_ws
// (L2-resident), A-tile staged in LDS in a-frag layout, epilogue fused in-register.

#define N_ROWS (64 * 4096)
#define HDIM 128
#define FDIM 64
#define KDIM 192
#define NKS 12          // k-steps of 16
#define M_TILE 32       // rows per block

typedef __bf16 bf16_t;
typedef __bf16 bf16x4 __attribute__((ext_vector_type(4)));
typedef __bf16 bf16x8 __attribute__((ext_vector_type(8)));
typedef float f32x16 __attribute__((ext_vector_type(16)));

// ---------------- prologue: swizzle weights fp32 -> bf16 b-frag layout ----------
// Bsw halfword index = ((ks*16 + ct)*64 + lane)*8 + j
//   holds B[k = ks*16 + (lane>>5)*8 + j][n = ct*32 + (lane&31)]
// where B = [Wx;Wh] concat over k (192) and gates concat over n (512).
__global__ void swizzle_weights(const float* __restrict__ Wxi, const float* __restrict__ Whi,
                                const float* __restrict__ Wxf, const float* __restrict__ Whf,
                                const float* __restrict__ Wxc, const float* __restrict__ Whc,
                                const float* __restrict__ Wxo, const float* __restrict__ Who,
                                bf16_t* __restrict__ Bsw) {
    int gid = blockIdx.x * 256 + threadIdx.x;      // 0 .. 12287
    int l  = gid & 63;
    int ct = (gid >> 6) & 15;
    int ks = gid >> 10;
    int kb = ks * 16 + (l >> 5) * 8;               // 8 consecutive k, never straddles 64
    int n  = ct * 32 + (l & 31);
    int g  = n >> 7;
    int c  = n & 127;
    const float* Wx = (g == 0) ? Wxi : (g == 1) ? Wxf : (g == 2) ? Wxc : Wxo;
    const float* Wh = (g == 0) ? Whi : (g == 1) ? Whf : (g == 2) ? Whc : Who;
    bf16x8 v;
#pragma unroll
    for (int j = 0; j < 8; ++j) {
        int k = kb + j;
        float f = (k < FDIM) ? Wx[k * HDIM + c] : Wh[(k - FDIM) * HDIM + c];
        v[j] = (bf16_t)f;
    }
    *(bf16x8*)(Bsw + (long)gid * 8) = v;
}

// ---------------- helpers ----------------
__device__ inline float fast_rcp(float x) { return __builtin_amdgcn_rcpf(x); }
__device__ inline float sigm(float x) {
    x = fminf(fmaxf(x, -30.f), 30.f);
    return fast_rcp(1.f + __expf(-x));
}
__device__ inline float tanh_f(float x) {
    x = fminf(fmaxf(x, -15.f), 15.f);
    float e = __expf(-2.f * x);
    return (1.f - e) * fast_rcp(1.f + e);
}

// store 4 floats (row, k0..k0+3) into a-frag LDS layout as bf16
// a_lds halfword index = ks*512 + (row + 32*((k>>3)&1))*8 + (k&7)
__device__ inline void store_a4(bf16_t* a_lds, int row, int k0, float4 v) {
    int ks = k0 >> 4, half = (k0 >> 3) & 1, j0 = k0 & 7;
    bf16_t* p = a_lds + ks * 512 + (row + 32 * half) * 8 + j0;
    bf16x4 w;
    w[0] = (bf16_t)v.x; w[1] = (bf16_t)v.y; w[2] = (bf16_t)v.z; w[3] = (bf16_t)v.w;
    *(bf16x4*)p = w;   // 8B aligned (j0 in {0,4})
}

// ---------------- main fused kernel ----------------
__global__ __launch_bounds__(256, 2)
void lstm_fused(const float* __restrict__ x, const float* __restrict__ h_t,
                const float* __restrict__ c_t,
                const float* __restrict__ b_i, const float* __restrict__ b_f,
                const float* __restrict__ b_c, const float* __restrict__ b_o,
                const bf16_t* __restrict__ Bsw,
                float* __restrict__ h_out, float* __restrict__ c_out) {
    __shared__ bf16_t a_lds[NKS * 512];            // 12 KB: [ks][lane][8]

    const int tid = threadIdx.x;
    const long row_base = (long)blockIdx.x * M_TILE;

    // stage x rows: 32 rows x 16 float4, coalesced
#pragma unroll
    for (int it = 0; it < 2; ++it) {
        int row = (tid >> 4) + it * 16;
        int k0  = (tid & 15) * 4;
        float4 v = *(const float4*)(x + (row_base + row) * FDIM + k0);
        store_a4(a_lds, row, k0, v);
    }
    // stage h rows: 32 rows x 32 float4, coalesced
#pragma unroll
    for (int it = 0; it < 4; ++it) {
        int row = (tid >> 5) + it * 8;
        int k0  = (tid & 31) * 4;
        float4 v = *(const float4*)(h_t + (row_base + row) * HDIM + k0);
        store_a4(a_lds, row, FDIM + k0, v);
    }
    __syncthreads();

    const int wave = tid >> 6;     // 0..3 -> col slice wave*32 of H
    const int lane = tid & 63;

    f32x16 acc0 = {}, acc1 = {}, acc2 = {}, acc3 = {};   // gates i,f,c,o

    const bf16_t* a_base = a_lds + lane * 8;
    const bf16_t* b_base = Bsw + wave * 512 + (long)lane * 8;

#pragma unroll
    for (int ks = 0; ks < NKS; ++ks) {
        bf16x8 a = *(const bf16x8*)(a_base + ks * 512);          // ds_read_b128
        const bf16_t* bp = b_base + ks * 8192;
        bf16x8 b0 = *(const bf16x8*)(bp);                        // gate i tile
        bf16x8 b1 = *(const bf16x8*)(bp + 2048);                 // gate f
        bf16x8 b2 = *(const bf16x8*)(bp + 4096);                 // gate c
        bf16x8 b3 = *(const bf16x8*)(bp + 6144);                 // gate o
        acc0 = __builtin_amdgcn_mfma_f32_32x32x16_bf16(a, b0, acc0, 0, 0, 0);
        acc1 = __builtin_amdgcn_mfma_f32_32x32x16_bf16(a, b1, acc1, 0, 0, 0);
        acc2 = __builtin_amdgcn_mfma_f32_32x32x16_bf16(a, b2, acc2, 0, 0, 0);
        acc3 = __builtin_amdgcn_mfma_f32_32x32x16_bf16(a, b3, acc3, 0, 0, 0);
    }

    // epilogue: C/D layout col = lane&31, row = (reg&3) + 8*(reg>>2) + 4*(lane>>5)
    const int col = wave * 32 + (lane & 31);
    const float bi = b_i[col], bf = b_f[col], bc = b_c[col], bo = b_o[col];
    const int rhalf = 4 * (lane >> 5);

#pragma unroll
    for (int r = 0; r < 16; ++r) {
        int row_l = (r & 3) + 8 * (r >> 2) + rhalf;
        long idx = (row_base + row_l) * HDIM + col;
        float gi = acc0[r] + bi;
        float gf = acc1[r] + bf;
        float gc = acc2[r] + bc;
        float go = acc3[r] + bo;
        float i_t = sigm(gi);
        float f_t = sigm(gf);
        float ch  = tanh_f(gc);
        float o_t = sigm(go);
        float cold = c_t[idx];
        float cn = f_t * cold + i_t * ch;
        float hn = o_t * tanh_f(cn);
        h_out[idx] = hn;
        c_out[idx] = cn;
    }
}

extern "C" void kernel_launch(void* const* d_in, const int* in_sizes, int n_in,
                              void* d_out, int out_size, void* d_ws, size_t ws_size,
                              hipStream_t stream) {
    const float* x    = (const float*)d_in[0];
    const float* h_t  = (const float*)d_in[1];
    const float* c_t  = (const float*)d_in[2];
    const float* W_xi = (const float*)d_in[3];
    const float* W_hi = (const float*)d_in[4];
    const float* b_i  = (const float*)d_in[5];
    const float* W_xf = (const float*)d_in[6];
    const float* W_hf = (const float*)d_in[7];
    const float* b_f  = (const float*)d_in[8];
    const float* W_xc = (const float*)d_in[9];
    const float* W_hc = (const float*)d_in[10];
    const float* b_c  = (const float*)d_in[11];
    const float* W_xo = (const float*)d_in[12];
    const float* W_ho = (const float*)d_in[13];
    const float* b_o  = (const float*)d_in[14];

    bf16_t* Bsw = (bf16_t*)d_ws;                  // 196608 bytes
    float* h_out = (float*)d_out;
    float* c_out = h_out + (long)N_ROWS * HDIM;

    swizzle_weights<<<48, 256, 0, stream>>>(W_xi, W_hi, W_xf, W_hf,
                                            W_xc, W_hc, W_xo, W_ho, Bsw);
    lstm_fused<<<N_ROWS / M_TILE, 256, 0, stream>>>(x, h_t, c_t, b_i, b_f, b_c, b_o,
                                                    Bsw, h_out, c_out);
}